// Round 7
// baseline (167.521 us; speedup 1.0000x reference)
//
#include <hip/hip_runtime.h>
#include <hip/hip_bf16.h>
#include <math.h>

#define BS   128
#define NT   25
#define CREC 107
#define CLOC 25
#define QN   1024      // H*W = 32*32 queries = columns of the transposed cost
#define INFD 1e18
// swizzled index for way[] (kills stride-4 bank conflicts)
#define WSTR 257
__device__ __forceinline__ int widx(int j) {   // j in 1..QN
    int q = j - 1;
    return (q & 3) * WSTR + (q >> 2);
}

// focal-loss matcher cost. Fast transcendentals: the matcher only needs the
// optimal assignment, robust to ~1e-7 cost perturbation (absmax 0.0 R4-R6).
__device__ __forceinline__ float focal_cost_f(float x) {
    float p   = 1.0f / (1.0f + __expf(-x));
    float neg = 0.75f * p * p * (-__logf(1.0f - p + 1e-8f));
    float pos = 0.25f * (1.0f - p) * (1.0f - p) * (-__logf(p + 1e-8f));
    return pos - neg;
}

// One block (256 thr) per batch. Fused:
//  Phase A: compute the full 25x1024 f32 cost tile into LDS (100 KB dynamic).
//  Phase B: row minima from the tile; greedy tight assignment.
//  Phase C: JV shortest-augmenting-path for argmin-collided rows — all cost
//           reads are ds_read_b128 from the tile (no global, no transcendentals
//           on the critical path), one barrier per iteration, u-updates hoisted
//           via delta-sum snapshots (bit-identical reduced costs).
// f64 duals on the same f32 cost values = exact numpy float64 JV semantics
// => the unique optimal assignment = scipy's answer.
__global__ __launch_bounds__(256)
void search_kernel(const float* __restrict__ rec, const float* __restrict__ loc,
                   const int* __restrict__ targets, int* __restrict__ pairq_g) {
    extern __shared__ float cost_s[];    // [NT][QN], 102400 B dynamic LDS
    const int b     = blockIdx.x;
    const int tid   = threadIdx.x;
    const int wave  = tid >> 6;
    const int lane  = tid & 63;
    const int qbase = tid << 2;          // first of the 4 owned columns

    __shared__ int    way_s[3 * WSTR + 256];
    __shared__ int    p_s[QN + 1];
    __shared__ double u_s[NT + 1];
    __shared__ int    t_s[NT];
    __shared__ float  bmv_s[NT][4];
    __shared__ int    bmq_s[NT][4];
    __shared__ float  rowmin_s[NT];
    __shared__ int    rowarg_s[NT];
    __shared__ int    unassigned_s[NT];
    __shared__ int    nun_s;
    __shared__ double candv_s[2][4];
    __shared__ int    candj_s[2][4];

    for (int j = tid; j <= QN; j += 256) p_s[j] = 0;
    if (tid < NT) t_s[tid] = targets[b * NT + tid];
    __syncthreads();

    const size_t rb0 = (size_t)b * CREC * QN;
    const size_t lb0 = (size_t)b * CLOC * QN;

    // ---- Phase A: cost tile into LDS (2-deep software pipeline) ----
    {
        float4 ra = *(const float4*)(rec + rb0 + (size_t)t_s[0] * QN + qbase);
        float4 la = *(const float4*)(loc + lb0 + qbase);
        for (int r = 0; r < NT; ++r) {
            float4 rn, ln;
            if (r + 1 < NT) {
                rn = *(const float4*)(rec + rb0 + (size_t)t_s[r + 1] * QN + qbase);
                ln = *(const float4*)(loc + lb0 + (size_t)(r + 1) * QN + qbase);
            }
            float4 c;
            c.x = 2.0f * focal_cost_f(ra.x) + focal_cost_f(la.x);
            c.y = 2.0f * focal_cost_f(ra.y) + focal_cost_f(la.y);
            c.z = 2.0f * focal_cost_f(ra.z) + focal_cost_f(la.z);
            c.w = 2.0f * focal_cost_f(ra.w) + focal_cost_f(la.w);
            *(float4*)(cost_s + (r << 10) + qbase) = c;
            if (r + 1 < NT) { ra = rn; la = ln; }
        }
    }
    __syncthreads();

    // ---- Phase B: row minima from the tile (first-index ties, exact) ----
    for (int r = 0; r < NT; ++r) {
        float4 c = *(const float4*)(cost_s + (r << 10) + qbase);
        float bv = c.x; int bq = qbase;
        if (c.y < bv) { bv = c.y; bq = qbase + 1; }
        if (c.z < bv) { bv = c.z; bq = qbase + 2; }
        if (c.w < bv) { bv = c.w; bq = qbase + 3; }
        #pragma unroll
        for (int off = 32; off; off >>= 1) {
            float ov = __shfl_xor(bv, off);
            int   oq = __shfl_xor(bq, off);
            if (ov < bv || (ov == bv && oq < bq)) { bv = ov; bq = oq; }
        }
        if (lane == 0) { bmv_s[r][wave] = bv; bmq_s[r][wave] = bq; }
    }
    __syncthreads();
    if (tid < NT) {      // cross-wave combine (wave q-ranges ordered)
        float bv = bmv_s[tid][0]; int bq = bmq_s[tid][0];
        #pragma unroll
        for (int w = 1; w < 4; ++w) {
            float ov = bmv_s[tid][w]; int oq = bmq_s[tid][w];
            if (ov < bv || (ov == bv && oq < bq)) { bv = ov; bq = oq; }
        }
        rowmin_s[tid] = bv; rowarg_s[tid] = bq;
    }
    __syncthreads();
    // greedy tight assignment (serial, trivial)
    if (tid == 0) {
        nun_s = 0;
        for (int r = 0; r < NT; ++r) {
            u_s[r + 1] = (double)rowmin_s[r];
            int j = rowarg_s[r] + 1;
            if (p_s[j] == 0) p_s[j] = r + 1;
            else             unassigned_s[nun_s++] = r + 1;
        }
    }
    __syncthreads();
    const int nun = nun_s;

    // ---- Phase C: JV searches, cost from LDS tile ----
    double v[4] = {0.0, 0.0, 0.0, 0.0};

    for (int s = 0; s < nun; ++s) {
        const int i = unassigned_s[s];
        double minv[4] = {INFD, INFD, INFD, INFD};
        double snap[4] = {0.0, 0.0, 0.0, 0.0};
        double dsum    = 0.0;
        unsigned usedmask = 0;
        int j0 = 0;
        int parity = 0;

        for (;;) {
            int i0;
            if (j0 == 0) {
                i0 = i;
            } else {
                int q0 = j0 - 1;
                if ((q0 >> 2) == tid) {          // owner thread of column q0
                    int m = q0 & 3;
                    usedmask |= 1u << m;
                    minv[m] = INFD;              // out of argmin & out of -=delta(free)
                    snap[m] = dsum;              // deltas before this iter don't apply
                }
                i0 = p_s[j0];                    // p stable within a search
            }
            const double ui0 = u_s[i0];          // read-only in-loop (pre-search value)
            const float4 c4 = *(const float4*)(cost_s + ((i0 - 1) << 10) + qbase);
            const float cf[4] = { c4.x, c4.y, c4.z, c4.w };

            // relax own free columns; lane-local lexicographic argmin
            double bestv = INFD; int bestj = QN + 2;
            #pragma unroll
            for (int m = 0; m < 4; ++m) {
                if (!(usedmask & (1u << m))) {
                    const int j = qbase + m + 1;
                    double cur = (double)cf[m] - ui0 - v[m];
                    if (cur < minv[m]) { minv[m] = cur; way_s[widx(j)] = j0; }
                    double mv = minv[m];
                    if (mv < bestv || (mv == bestv && j < bestj)) { bestv = mv; bestj = j; }
                }
            }
            #pragma unroll
            for (int off = 32; off; off >>= 1) {
                double ov = __shfl_xor(bestv, off);
                int    oj = __shfl_xor(bestj, off);
                if (ov < bestv || (ov == bestv && oj < bestj)) { bestv = ov; bestj = oj; }
            }
            if (lane == 0) { candv_s[parity][wave] = bestv; candj_s[parity][wave] = bestj; }
            __syncthreads();                     // the ONE barrier per iteration
            double delta = candv_s[parity][0]; int j1 = candj_s[parity][0];
            #pragma unroll
            for (int w = 1; w < 4; ++w) {
                double dv = candv_s[parity][w]; int dj = candj_s[parity][w];
                if (dv < delta || (dv == delta && dj < j1)) { delta = dv; j1 = dj; }
            }
            parity ^= 1;
            dsum += delta;

            #pragma unroll
            for (int m = 0; m < 4; ++m) {
                if (usedmask & (1u << m)) v[m]    -= delta;
                else                      minv[m] -= delta;
            }
            j0 = j1;
            if (p_s[j0] == 0) break;
        }

        // end-of-search u updates (distinct rows => conflict-free LDS RMW)
        if (tid == 0) u_s[i] += dsum;
        unsigned mm = usedmask;
        while (mm) {
            int m = __ffs(mm) - 1; mm &= mm - 1;
            u_s[p_s[qbase + m + 1]] += dsum - snap[m];
        }
        __syncthreads();
        // augment along the alternating path (short, sequential)
        if (tid == 0) {
            int jj = j0;
            while (jj != 0) {
                int jn = way_s[widx(jj)];
                p_s[jj] = (jn == 0) ? i : p_s[jn];
                jj = jn;
            }
        }
        __syncthreads();
    }

    // emit matched pairs: column j assigned to target row p_s[j]-1
    for (int j = tid + 1; j <= QN; j += 256)
        if (p_s[j] > 0) pairq_g[b * NT + (p_s[j] - 1)] = j - 1;
}

// One wave per matched pair: CE over 107 (rec) and 25 (loc) classes at the
// matched query column. 3200 blocks => full latency hiding for the gathers.
__global__ __launch_bounds__(64)
void loss_kernel(const float* __restrict__ rec, const float* __restrict__ loc,
                 const int* __restrict__ targets, const int* __restrict__ pairq_g,
                 float* __restrict__ partial) {
    const int pid  = blockIdx.x;          // b*NT + t
    const int b    = pid / NT, t = pid % NT;
    const int lane = threadIdx.x;
    const int q    = pairq_g[pid];

    // rec CE over 107 classes at query q
    const float* rb = rec + (size_t)b * CREC * QN + q;
    float x0 = (lane < CREC)      ? rb[(size_t)lane * QN]        : -1e30f;
    float x1 = (lane + 64 < CREC) ? rb[(size_t)(lane + 64) * QN] : -1e30f;
    float mx = fmaxf(x0, x1);
    #pragma unroll
    for (int off = 32; off; off >>= 1) mx = fmaxf(mx, __shfl_xor(mx, off));
    float e = 0.0f;
    if (lane < CREC)      e += expf(x0 - mx);
    if (lane + 64 < CREC) e += expf(x1 - mx);
    #pragma unroll
    for (int off = 32; off; off >>= 1) e += __shfl_xor(e, off);
    float lse = mx + logf(e);

    // loc CE over 25 classes at query q, label = t
    const float* lb = loc + (size_t)b * CLOC * QN + q;
    float y = (lane < CLOC) ? lb[(size_t)lane * QN] : -1e30f;
    float my = y;
    #pragma unroll
    for (int off = 32; off; off >>= 1) my = fmaxf(my, __shfl_xor(my, off));
    float ey = (lane < CLOC) ? expf(y - my) : 0.0f;
    #pragma unroll
    for (int off = 32; off; off >>= 1) ey += __shfl_xor(ey, off);
    float lsey = my + logf(ey);

    if (lane == 0) {
        int lab = targets[pid];
        partial[pid]           = lse  - rb[(size_t)lab * QN];
        partial[BS * NT + pid] = lsey - lb[(size_t)t * QN];
    }
}

__global__ __launch_bounds__(256)
void finalize_kernel(const float* __restrict__ partial, float* __restrict__ out) {
    const int tid = threadIdx.x;
    float s0 = 0.0f, s1 = 0.0f;
    for (int i = tid; i < BS * NT; i += 256) {
        s0 += partial[i];
        s1 += partial[BS * NT + i];
    }
    __shared__ float a0[4], a1[4];
    #pragma unroll
    for (int off = 32; off; off >>= 1) { s0 += __shfl_xor(s0, off); s1 += __shfl_xor(s1, off); }
    if ((tid & 63) == 0) { a0[tid >> 6] = s0; a1[tid >> 6] = s1; }
    __syncthreads();
    if (tid == 0) {
        out[0] = (a0[0] + a0[1] + a0[2] + a0[3]) * (1.0f / (BS * NT));
        out[1] = (a1[0] + a1[1] + a1[2] + a1[3]) * (1.0f / (BS * NT));
    }
}

extern "C" void kernel_launch(void* const* d_in, const int* in_sizes, int n_in,
                              void* d_out, int out_size, void* d_ws, size_t ws_size,
                              hipStream_t stream) {
    (void)in_sizes; (void)n_in; (void)out_size; (void)ws_size;
    const float* rec     = (const float*)d_in[0];
    const float* loc     = (const float*)d_in[1];
    const int*   targets = (const int*)d_in[2];
    float* out = (float*)d_out;

    // workspace layout: pairq i32[3200] | partial f32[6400]
    int*   pairq_g = (int*)d_ws;
    float* partial = (float*)(pairq_g + BS * NT);

    const int tile_bytes = NT * QN * (int)sizeof(float);   // 102400 B dynamic LDS
    // sticky, idempotent, not a stream op — safe under graph capture; result ignored
    (void)hipFuncSetAttribute((const void*)search_kernel,
                              hipFuncAttributeMaxDynamicSharedMemorySize, tile_bytes);

    hipLaunchKernelGGL(search_kernel, dim3(BS), dim3(256), tile_bytes, stream,
                       rec, loc, targets, pairq_g);
    hipLaunchKernelGGL(loss_kernel, dim3(BS * NT), dim3(64), 0, stream,
                       rec, loc, targets, pairq_g, partial);
    hipLaunchKernelGGL(finalize_kernel, dim3(1), dim3(256), 0, stream,
                       partial, out);
}

// Round 8
// 158.472 us; speedup vs baseline: 1.0571x; 1.0571x over previous
//
#include <hip/hip_runtime.h>
#include <hip/hip_bf16.h>
#include <math.h>

#define BS   128
#define NT   25
#define CREC 107
#define CLOC 25
#define QN   1024      // H*W = 32*32 queries = columns of the transposed cost
#define INFD 1e18
// swizzled index for way[] (kills stride-4 bank conflicts)
#define WSTR 257
__device__ __forceinline__ int widx(int j) {   // j in 1..QN
    int q = j - 1;
    return (q & 3) * WSTR + (q >> 2);
}

// focal-loss matcher cost. Fast transcendentals: the matcher only needs the
// optimal assignment, robust to ~1e-7 cost perturbation (absmax 0.0 R4-R7).
__device__ __forceinline__ float focal_cost_f(float x) {
    float p   = 1.0f / (1.0f + __expf(-x));
    float neg = 0.75f * p * p * (-__logf(1.0f - p + 1e-8f));
    float pos = 0.25f * (1.0f - p) * (1.0f - p) * (-__logf(p + 1e-8f));
    return pos - neg;
}

// One block (256 thr) per batch.
//  Phase A (4 waves): 25x1024 f32 cost tile into LDS (100 KB dynamic).
//  Phase B (4 waves): row minima (5-wide interleaved butterflies) + greedy.
//  Phase C (WAVE 0 ONLY): JV shortest-augmenting-path for collided rows.
//    KPL=16 cols/lane in registers, no barriers, no cross-wave traffic.
//    Wave argmin: f32-screened (monotone f64->f32) butterfly + exact f64
//    resolve of the candidate mask => bit-identical lexicographic argmin.
// f64 duals on the same f32 cost values = exact numpy float64 JV semantics
// => the unique optimal assignment = scipy's answer.
__global__ __launch_bounds__(256, 1)
void search_kernel(const float* __restrict__ rec, const float* __restrict__ loc,
                   const int* __restrict__ targets, int* __restrict__ pairq_g) {
    extern __shared__ float cost_s[];    // [NT][QN], 102400 B dynamic LDS
    const int b     = blockIdx.x;
    const int tid   = threadIdx.x;
    const int wave  = tid >> 6;
    const int lane  = tid & 63;
    const int qbase = tid << 2;          // phase A/B: 4 cols per THREAD

    __shared__ int    way_s[4 * WSTR];
    __shared__ int    p_s[QN + 1];
    __shared__ double u_s[NT + 1];
    __shared__ double snap_s[QN];
    __shared__ int    t_s[NT];
    __shared__ float  bmv_s[NT][4];
    __shared__ int    bmq_s[NT][4];
    __shared__ float  rowmin_s[NT];
    __shared__ int    rowarg_s[NT];
    __shared__ int    unassigned_s[NT];
    __shared__ int    nun_s;

    for (int j = tid; j <= QN; j += 256) p_s[j] = 0;
    if (tid < NT) t_s[tid] = targets[b * NT + tid];
    __syncthreads();

    const size_t rb0 = (size_t)b * CREC * QN;
    const size_t lb0 = (size_t)b * CLOC * QN;

    // ---- Phase A: cost tile into LDS (2-deep software pipeline) ----
    {
        float4 ra = *(const float4*)(rec + rb0 + (size_t)t_s[0] * QN + qbase);
        float4 la = *(const float4*)(loc + lb0 + qbase);
        for (int r = 0; r < NT; ++r) {
            float4 rn, ln;
            if (r + 1 < NT) {
                rn = *(const float4*)(rec + rb0 + (size_t)t_s[r + 1] * QN + qbase);
                ln = *(const float4*)(loc + lb0 + (size_t)(r + 1) * QN + qbase);
            }
            float4 c;
            c.x = 2.0f * focal_cost_f(ra.x) + focal_cost_f(la.x);
            c.y = 2.0f * focal_cost_f(ra.y) + focal_cost_f(la.y);
            c.z = 2.0f * focal_cost_f(ra.z) + focal_cost_f(la.z);
            c.w = 2.0f * focal_cost_f(ra.w) + focal_cost_f(la.w);
            *(float4*)(cost_s + (r << 10) + qbase) = c;
            if (r + 1 < NT) { ra = rn; la = ln; }
        }
    }
    __syncthreads();

    // ---- Phase B: row minima, 5 independent butterflies in flight ----
    for (int r0 = 0; r0 < NT; r0 += 5) {
        float bv[5]; int bq[5];
        #pragma unroll
        for (int rr = 0; rr < 5; ++rr) {
            float4 c = *(const float4*)(cost_s + ((r0 + rr) << 10) + qbase);
            float v = c.x; int q = qbase;
            if (c.y < v) { v = c.y; q = qbase + 1; }
            if (c.z < v) { v = c.z; q = qbase + 2; }
            if (c.w < v) { v = c.w; q = qbase + 3; }
            bv[rr] = v; bq[rr] = q;
        }
        #pragma unroll
        for (int off = 32; off; off >>= 1) {
            #pragma unroll
            for (int rr = 0; rr < 5; ++rr) {
                float ov = __shfl_xor(bv[rr], off);
                int   oq = __shfl_xor(bq[rr], off);
                if (ov < bv[rr] || (ov == bv[rr] && oq < bq[rr])) { bv[rr] = ov; bq[rr] = oq; }
            }
        }
        if (lane == 0) {
            #pragma unroll
            for (int rr = 0; rr < 5; ++rr) { bmv_s[r0 + rr][wave] = bv[rr]; bmq_s[r0 + rr][wave] = bq[rr]; }
        }
    }
    __syncthreads();
    if (tid < NT) {      // cross-wave combine (wave q-ranges ordered)
        float bv = bmv_s[tid][0]; int bq = bmq_s[tid][0];
        #pragma unroll
        for (int w = 1; w < 4; ++w) {
            float ov = bmv_s[tid][w]; int oq = bmq_s[tid][w];
            if (ov < bv || (ov == bv && oq < bq)) { bv = ov; bq = oq; }
        }
        rowmin_s[tid] = bv; rowarg_s[tid] = bq;
    }
    __syncthreads();
    if (tid == 0) {      // greedy tight assignment (serial, trivial)
        nun_s = 0;
        for (int r = 0; r < NT; ++r) {
            u_s[r + 1] = (double)rowmin_s[r];
            int j = rowarg_s[r] + 1;
            if (p_s[j] == 0) p_s[j] = r + 1;
            else             unassigned_s[nun_s++] = r + 1;
        }
    }
    __syncthreads();
    const int nun = nun_s;

    // ---- Phase C: single-wave JV searches (wave 0), cost from LDS tile ----
    // lane owns cols q = 4*lane + m + 256*g, slot k = 4*g + m
    if (wave == 0 && nun > 0) {
        double v[16], minv[16];
        #pragma unroll
        for (int k = 0; k < 16; ++k) v[k] = 0.0;

        for (int s = 0; s < nun; ++s) {
            const int i = unassigned_s[s];
            #pragma unroll
            for (int k = 0; k < 16; ++k) minv[k] = INFD;
            unsigned usedmask = 0;
            double dsum = 0.0;
            int j0 = 0;

            for (;;) {
                int i0;
                if (j0 == 0) {
                    i0 = i;
                } else {
                    int q0 = j0 - 1;
                    if (((q0 & 255) >> 2) == lane) {     // owner lane of column q0
                        int kk = ((q0 >> 8) << 2) | (q0 & 3);
                        #pragma unroll
                        for (int k = 0; k < 16; ++k)
                            if (k == kk) { usedmask |= 1u << k; minv[k] = INFD; }
                        snap_s[q0] = dsum;               // deltas before now don't apply
                    }
                    i0 = p_s[j0];                        // stable within a search
                }
                const double ui0 = u_s[i0];              // pre-search value (read-only)
                const float* crow = cost_s + ((i0 - 1) << 10);
                float cf[16];
                #pragma unroll
                for (int g = 0; g < 4; ++g) {
                    float4 c4 = *(const float4*)(crow + 4 * lane + 256 * g);
                    cf[4 * g + 0] = c4.x; cf[4 * g + 1] = c4.y;
                    cf[4 * g + 2] = c4.z; cf[4 * g + 3] = c4.w;
                }

                // relax own free columns; lane-local lexicographic argmin
                double bestv = INFD; int bestj = QN + 2;
                #pragma unroll
                for (int k = 0; k < 16; ++k) {
                    if (!(usedmask & (1u << k))) {
                        const int j = 1 + 4 * lane + (k & 3) + 256 * (k >> 2);
                        double cur = (double)cf[k] - ui0 - v[k];
                        if (cur < minv[k]) { minv[k] = cur; way_s[widx(j)] = j0; }
                        double mv = minv[k];
                        if (mv < bestv || (mv == bestv && j < bestj)) { bestv = mv; bestj = j; }
                    }
                }

                // f32-screened wave argmin: monotone screen, exact resolve
                float own = (float)bestv;
                float red = own;
                #pragma unroll
                for (int off = 32; off; off >>= 1) red = fminf(red, __shfl_xor(red, off));
                unsigned long long mask = __ballot(own == red);
                double gv = INFD; int gj = QN + 2;
                while (mask) {                           // ~1 iteration typical
                    int l = __ffsll(mask) - 1; mask &= mask - 1;
                    double vv = __shfl(bestv, l);
                    int    jj = __shfl(bestj, l);
                    if (vv < gv || (vv == gv && jj < gj)) { gv = vv; gj = jj; }
                }
                const double delta = gv;
                const int j1 = gj;
                dsum += delta;

                #pragma unroll
                for (int k = 0; k < 16; ++k) {
                    if (usedmask & (1u << k)) v[k]    -= delta;
                    else                      minv[k] -= delta;
                }
                j0 = j1;
                if (p_s[j0] == 0) break;
            }
            __threadfence_block();     // order way_s/snap_s before u-update/augment

            // end-of-search u updates (distinct rows => distinct LDS addrs)
            if (lane == 0) u_s[i] += dsum;
            unsigned mm = usedmask;
            while (mm) {
                int k = __ffs(mm) - 1; mm &= mm - 1;
                int q = 4 * lane + (k & 3) + 256 * (k >> 2);
                u_s[p_s[q + 1]] += dsum - snap_s[q];
            }
            __threadfence_block();
            if (lane == 0) {           // augment along the alternating path
                int jj = j0;
                while (jj != 0) {
                    int jn = way_s[widx(jj)];
                    p_s[jj] = (jn == 0) ? i : p_s[jn];
                    jj = jn;
                }
            }
            __threadfence_block();     // p_s visible to whole wave for next search
        }
    }
    __syncthreads();

    // emit matched pairs: column j assigned to target row p_s[j]-1
    for (int j = tid + 1; j <= QN; j += 256)
        if (p_s[j] > 0) pairq_g[b * NT + (p_s[j] - 1)] = j - 1;
}

// One wave per matched pair: CE over 107 (rec) and 25 (loc) classes at the
// matched query column. 3200 blocks => full latency hiding for the gathers.
__global__ __launch_bounds__(64)
void loss_kernel(const float* __restrict__ rec, const float* __restrict__ loc,
                 const int* __restrict__ targets, const int* __restrict__ pairq_g,
                 float* __restrict__ partial) {
    const int pid  = blockIdx.x;          // b*NT + t
    const int b    = pid / NT, t = pid % NT;
    const int lane = threadIdx.x;
    const int q    = pairq_g[pid];

    // rec CE over 107 classes at query q
    const float* rb = rec + (size_t)b * CREC * QN + q;
    float x0 = (lane < CREC)      ? rb[(size_t)lane * QN]        : -1e30f;
    float x1 = (lane + 64 < CREC) ? rb[(size_t)(lane + 64) * QN] : -1e30f;
    float mx = fmaxf(x0, x1);
    #pragma unroll
    for (int off = 32; off; off >>= 1) mx = fmaxf(mx, __shfl_xor(mx, off));
    float e = 0.0f;
    if (lane < CREC)      e += expf(x0 - mx);
    if (lane + 64 < CREC) e += expf(x1 - mx);
    #pragma unroll
    for (int off = 32; off; off >>= 1) e += __shfl_xor(e, off);
    float lse = mx + logf(e);

    // loc CE over 25 classes at query q, label = t
    const float* lb = loc + (size_t)b * CLOC * QN + q;
    float y = (lane < CLOC) ? lb[(size_t)lane * QN] : -1e30f;
    float my = y;
    #pragma unroll
    for (int off = 32; off; off >>= 1) my = fmaxf(my, __shfl_xor(my, off));
    float ey = (lane < CLOC) ? expf(y - my) : 0.0f;
    #pragma unroll
    for (int off = 32; off; off >>= 1) ey += __shfl_xor(ey, off);
    float lsey = my + logf(ey);

    if (lane == 0) {
        int lab = targets[pid];
        partial[pid]           = lse  - rb[(size_t)lab * QN];
        partial[BS * NT + pid] = lsey - lb[(size_t)t * QN];
    }
}

__global__ __launch_bounds__(256)
void finalize_kernel(const float* __restrict__ partial, float* __restrict__ out) {
    const int tid = threadIdx.x;
    float s0 = 0.0f, s1 = 0.0f;
    for (int i = tid; i < BS * NT; i += 256) {
        s0 += partial[i];
        s1 += partial[BS * NT + i];
    }
    __shared__ float a0[4], a1[4];
    #pragma unroll
    for (int off = 32; off; off >>= 1) { s0 += __shfl_xor(s0, off); s1 += __shfl_xor(s1, off); }
    if ((tid & 63) == 0) { a0[tid >> 6] = s0; a1[tid >> 6] = s1; }
    __syncthreads();
    if (tid == 0) {
        out[0] = (a0[0] + a0[1] + a0[2] + a0[3]) * (1.0f / (BS * NT));
        out[1] = (a1[0] + a1[1] + a1[2] + a1[3]) * (1.0f / (BS * NT));
    }
}

extern "C" void kernel_launch(void* const* d_in, const int* in_sizes, int n_in,
                              void* d_out, int out_size, void* d_ws, size_t ws_size,
                              hipStream_t stream) {
    (void)in_sizes; (void)n_in; (void)out_size; (void)ws_size;
    const float* rec     = (const float*)d_in[0];
    const float* loc     = (const float*)d_in[1];
    const int*   targets = (const int*)d_in[2];
    float* out = (float*)d_out;

    // workspace layout: pairq i32[3200] | partial f32[6400]
    int*   pairq_g = (int*)d_ws;
    float* partial = (float*)(pairq_g + BS * NT);

    const int tile_bytes = NT * QN * (int)sizeof(float);   // 102400 B dynamic LDS
    // sticky, idempotent, not a stream op — safe under graph capture
    (void)hipFuncSetAttribute((const void*)search_kernel,
                              hipFuncAttributeMaxDynamicSharedMemorySize, tile_bytes);

    hipLaunchKernelGGL(search_kernel, dim3(BS), dim3(256), tile_bytes, stream,
                       rec, loc, targets, pairq_g);
    hipLaunchKernelGGL(loss_kernel, dim3(BS * NT), dim3(64), 0, stream,
                       rec, loc, targets, pairq_g, partial);
    hipLaunchKernelGGL(finalize_kernel, dim3(1), dim3(256), 0, stream,
                       partial, out);
}

// Round 9
// 141.472 us; speedup vs baseline: 1.1841x; 1.1202x over previous
//
#include <hip/hip_runtime.h>
#include <hip/hip_bf16.h>
#include <math.h>

#define BS   128
#define NT   25
#define CREC 107
#define CLOC 25
#define QN   1024      // H*W = 32*32 queries = columns of the transposed cost
#define INFD 1e18
// swizzled index for way[] (kills stride-4 bank conflicts)
#define WSTR 257
__device__ __forceinline__ int widx(int j) {   // j in 1..QN
    int q = j - 1;
    return (q & 3) * WSTR + (q >> 2);
}

// focal-loss matcher cost. Fast transcendentals: the matcher only needs the
// optimal assignment, robust to ~1e-7 cost perturbation (absmax 0.0 R4-R8).
__device__ __forceinline__ float focal_cost_f(float x) {
    float p   = 1.0f / (1.0f + __expf(-x));
    float neg = 0.75f * p * p * (-__logf(1.0f - p + 1e-8f));
    float pos = 0.25f * (1.0f - p) * (1.0f - p) * (-__logf(p + 1e-8f));
    return pos - neg;
}

// One block per cost row (b,r): computes the row's costs, STORES them to
// global (L3-hot for search), and reduces min + first-index argmin exactly.
__global__ __launch_bounds__(256)
void rowmin_kernel(const float* __restrict__ rec, const float* __restrict__ loc,
                   const int* __restrict__ targets, float* __restrict__ cost_g,
                   float* __restrict__ rowmin_g, int* __restrict__ rowarg_g) {
    const int pid   = blockIdx.x;          // b*NT + r
    const int b     = pid / NT, r = pid % NT;
    const int tid   = threadIdx.x;
    const int qbase = tid << 2;
    const int tc    = targets[pid];

    float4 r4 = *(const float4*)(rec + ((size_t)b * CREC + tc) * QN + qbase);
    float4 l4 = *(const float4*)(loc + ((size_t)b * CLOC + r)  * QN + qbase);
    float4 c;
    c.x = 2.0f * focal_cost_f(r4.x) + focal_cost_f(l4.x);
    c.y = 2.0f * focal_cost_f(r4.y) + focal_cost_f(l4.y);
    c.z = 2.0f * focal_cost_f(r4.z) + focal_cost_f(l4.z);
    c.w = 2.0f * focal_cost_f(r4.w) + focal_cost_f(l4.w);
    *(float4*)(cost_g + ((size_t)pid << 10) + qbase) = c;

    float bv = c.x; int bq = qbase;
    if (c.y < bv) { bv = c.y; bq = qbase + 1; }     // strict < => first index
    if (c.z < bv) { bv = c.z; bq = qbase + 2; }
    if (c.w < bv) { bv = c.w; bq = qbase + 3; }
    #pragma unroll
    for (int off = 32; off; off >>= 1) {
        float ov = __shfl_xor(bv, off);
        int   oq = __shfl_xor(bq, off);
        if (ov < bv || (ov == bv && oq < bq)) { bv = ov; bq = oq; }
    }
    __shared__ float bmv[4];
    __shared__ int   bmq[4];
    if ((tid & 63) == 0) { bmv[tid >> 6] = bv; bmq[tid >> 6] = bq; }
    __syncthreads();
    if (tid == 0) {
        float fv = bmv[0]; int fq = bmq[0];
        #pragma unroll
        for (int w = 1; w < 4; ++w) {
            float ov = bmv[w]; int oq = bmq[w];
            if (ov < fv || (ov == fv && oq < fq)) { fv = ov; fq = oq; }
        }
        rowmin_g[pid] = fv; rowarg_g[pid] = fq;
    }
}

// One block (4 waves) per batch: greedy tight assignment from row minima,
// then JV shortest-augmenting-path for argmin-collided rows (~1-3/batch,
// ~2-4 iters each). Cost rows read from the precomputed global matrix
// (L3-hot). One barrier per iteration; u-updates hoisted via delta-sum
// snapshots (bit-identical reduced costs). Wave argmin: f32-screened
// (monotone f64->f32) fminf butterfly + exact f64 resolve of the ballot
// candidates + exact cross-wave combine => bit-identical lexicographic
// argmin. f64 duals on the same f32 cost values = exact numpy float64 JV
// semantics => the unique optimal assignment = scipy's answer.
__global__ __launch_bounds__(256)
void search_kernel(const float* __restrict__ cost_g,
                   const float* __restrict__ rowmin_g, const int* __restrict__ rowarg_g,
                   int* __restrict__ pairq_g) {
    const int b     = blockIdx.x;
    const int tid   = threadIdx.x;
    const int wave  = tid >> 6;
    const int lane  = tid & 63;
    const int qbase = tid << 2;          // first of the 4 owned columns

    __shared__ int    way_s[4 * WSTR];
    __shared__ int    p_s[QN + 1];
    __shared__ double u_s[NT + 1];
    __shared__ float  rowmin_s[NT];
    __shared__ int    rowarg_s[NT];
    __shared__ int    unassigned_s[NT];
    __shared__ int    nun_s;
    __shared__ double candv_s[2][4];
    __shared__ int    candj_s[2][4];

    for (int j = tid; j <= QN; j += 256) p_s[j] = 0;
    if (tid < NT) {
        rowmin_s[tid] = rowmin_g[b * NT + tid];
        rowarg_s[tid] = rowarg_g[b * NT + tid];
    }
    __syncthreads();

    // greedy tight assignment (serial, trivial)
    if (tid == 0) {
        nun_s = 0;
        for (int r = 0; r < NT; ++r) {
            u_s[r + 1] = (double)rowmin_s[r];
            int j = rowarg_s[r] + 1;
            if (p_s[j] == 0) p_s[j] = r + 1;
            else             unassigned_s[nun_s++] = r + 1;
        }
    }
    __syncthreads();
    const int nun = nun_s;

    const float* cb = cost_g + ((size_t)b * NT << 10);

    double v[4] = {0.0, 0.0, 0.0, 0.0};

    for (int s = 0; s < nun; ++s) {
        const int i = unassigned_s[s];
        double minv[4] = {INFD, INFD, INFD, INFD};
        double snap[4] = {0.0, 0.0, 0.0, 0.0};
        double dsum    = 0.0;
        unsigned usedmask = 0;
        int j0 = 0;
        int parity = 0;

        for (;;) {
            int i0;
            if (j0 == 0) {
                i0 = i;
            } else {
                int q0 = j0 - 1;
                if ((q0 >> 2) == tid) {          // owner thread of column q0
                    int m = q0 & 3;
                    usedmask |= 1u << m;
                    minv[m] = INFD;              // out of argmin & out of -=delta(free)
                    snap[m] = dsum;              // deltas before this iter don't apply
                }
                i0 = p_s[j0];                    // p stable within a search
            }
            const double ui0 = u_s[i0];          // pre-search value (read-only in-loop)
            const float4 c4 = *(const float4*)(cb + ((size_t)(i0 - 1) << 10) + qbase);
            const float cf[4] = { c4.x, c4.y, c4.z, c4.w };

            // relax own free columns; lane-local lexicographic argmin (f64 exact)
            double bestv = INFD; int bestj = QN + 2;
            #pragma unroll
            for (int m = 0; m < 4; ++m) {
                if (!(usedmask & (1u << m))) {
                    const int j = qbase + m + 1;
                    double cur = (double)cf[m] - ui0 - v[m];
                    if (cur < minv[m]) { minv[m] = cur; way_s[widx(j)] = j0; }
                    double mv = minv[m];
                    if (mv < bestv || (mv == bestv && j < bestj)) { bestv = mv; bestj = j; }
                }
            }

            // f32-screened wave argmin: monotone screen, exact f64 resolve
            float own32 = (float)bestv;
            float w32 = own32;
            #pragma unroll
            for (int off = 32; off; off >>= 1) w32 = fminf(w32, __shfl_xor(w32, off));
            unsigned long long cand = __ballot(own32 == w32);
            double wv = INFD; int wj = QN + 2;
            while (cand) {                       // ~1 iteration typical, wave-uniform
                int l = __ffsll(cand) - 1; cand &= cand - 1;
                double vv = __shfl(bestv, l);
                int    jj = __shfl(bestj, l);
                if (vv < wv || (vv == wv && jj < wj)) { wv = vv; wj = jj; }
            }
            if (lane == 0) { candv_s[parity][wave] = wv; candj_s[parity][wave] = wj; }
            __syncthreads();                     // the ONE barrier per iteration
            double delta = candv_s[parity][0]; int j1 = candj_s[parity][0];
            #pragma unroll
            for (int w = 1; w < 4; ++w) {
                double dv = candv_s[parity][w]; int dj = candj_s[parity][w];
                if (dv < delta || (dv == delta && dj < j1)) { delta = dv; j1 = dj; }
            }
            parity ^= 1;
            dsum += delta;

            #pragma unroll
            for (int m = 0; m < 4; ++m) {
                if (usedmask & (1u << m)) v[m]    -= delta;
                else                      minv[m] -= delta;
            }
            j0 = j1;
            if (p_s[j0] == 0) break;
        }

        // end-of-search u updates: distinct rows => distinct LDS addrs, no race
        if (tid == 0) u_s[i] += dsum;
        unsigned mm = usedmask;
        while (mm) {
            int m = __ffs(mm) - 1; mm &= mm - 1;
            u_s[p_s[qbase + m + 1]] += dsum - snap[m];
        }
        __syncthreads();
        // augment along the alternating path (short, sequential)
        if (tid == 0) {
            int jj = j0;
            while (jj != 0) {
                int jn = way_s[widx(jj)];
                p_s[jj] = (jn == 0) ? i : p_s[jn];
                jj = jn;
            }
        }
        __syncthreads();
    }

    // emit matched pairs: column j assigned to target row p_s[j]-1
    for (int j = tid + 1; j <= QN; j += 256)
        if (p_s[j] > 0) pairq_g[b * NT + (p_s[j] - 1)] = j - 1;
}

// One wave per matched pair: CE over 107 (rec) and 25 (loc) classes at the
// matched query column. 3200 blocks => full latency hiding for the gathers.
__global__ __launch_bounds__(64)
void loss_kernel(const float* __restrict__ rec, const float* __restrict__ loc,
                 const int* __restrict__ targets, const int* __restrict__ pairq_g,
                 float* __restrict__ partial) {
    const int pid  = blockIdx.x;          // b*NT + t
    const int b    = pid / NT, t = pid % NT;
    const int lane = threadIdx.x;
    const int q    = pairq_g[pid];

    // rec CE over 107 classes at query q
    const float* rb = rec + (size_t)b * CREC * QN + q;
    float x0 = (lane < CREC)      ? rb[(size_t)lane * QN]        : -1e30f;
    float x1 = (lane + 64 < CREC) ? rb[(size_t)(lane + 64) * QN] : -1e30f;
    float mx = fmaxf(x0, x1);
    #pragma unroll
    for (int off = 32; off; off >>= 1) mx = fmaxf(mx, __shfl_xor(mx, off));
    float e = 0.0f;
    if (lane < CREC)      e += expf(x0 - mx);
    if (lane + 64 < CREC) e += expf(x1 - mx);
    #pragma unroll
    for (int off = 32; off; off >>= 1) e += __shfl_xor(e, off);
    float lse = mx + logf(e);

    // loc CE over 25 classes at query q, label = t
    const float* lb = loc + (size_t)b * CLOC * QN + q;
    float y = (lane < CLOC) ? lb[(size_t)lane * QN] : -1e30f;
    float my = y;
    #pragma unroll
    for (int off = 32; off; off >>= 1) my = fmaxf(my, __shfl_xor(my, off));
    float ey = (lane < CLOC) ? expf(y - my) : 0.0f;
    #pragma unroll
    for (int off = 32; off; off >>= 1) ey += __shfl_xor(ey, off);
    float lsey = my + logf(ey);

    if (lane == 0) {
        int lab = targets[pid];
        partial[pid]           = lse  - rb[(size_t)lab * QN];
        partial[BS * NT + pid] = lsey - lb[(size_t)t * QN];
    }
}

__global__ __launch_bounds__(256)
void finalize_kernel(const float* __restrict__ partial, float* __restrict__ out) {
    const int tid = threadIdx.x;
    float s0 = 0.0f, s1 = 0.0f;
    for (int i = tid; i < BS * NT; i += 256) {
        s0 += partial[i];
        s1 += partial[BS * NT + i];
    }
    __shared__ float a0[4], a1[4];
    #pragma unroll
    for (int off = 32; off; off >>= 1) { s0 += __shfl_xor(s0, off); s1 += __shfl_xor(s1, off); }
    if ((tid & 63) == 0) { a0[tid >> 6] = s0; a1[tid >> 6] = s1; }
    __syncthreads();
    if (tid == 0) {
        out[0] = (a0[0] + a0[1] + a0[2] + a0[3]) * (1.0f / (BS * NT));
        out[1] = (a1[0] + a1[1] + a1[2] + a1[3]) * (1.0f / (BS * NT));
    }
}

extern "C" void kernel_launch(void* const* d_in, const int* in_sizes, int n_in,
                              void* d_out, int out_size, void* d_ws, size_t ws_size,
                              hipStream_t stream) {
    (void)in_sizes; (void)n_in; (void)out_size; (void)ws_size;
    const float* rec     = (const float*)d_in[0];
    const float* loc     = (const float*)d_in[1];
    const int*   targets = (const int*)d_in[2];
    float* out = (float*)d_out;

    // ws layout: cost f32[BS*NT*QN]=13.1MB | rowmin f32[3200] | rowarg i32[3200]
    //            | pairq i32[3200] | partial f32[6400]
    float* cost_g   = (float*)d_ws;
    float* rowmin_g = cost_g + (size_t)BS * NT * QN;
    int*   rowarg_g = (int*)(rowmin_g + BS * NT);
    int*   pairq_g  = rowarg_g + BS * NT;
    float* partial  = (float*)(pairq_g + BS * NT);

    hipLaunchKernelGGL(rowmin_kernel, dim3(BS * NT), dim3(256), 0, stream,
                       rec, loc, targets, cost_g, rowmin_g, rowarg_g);
    hipLaunchKernelGGL(search_kernel, dim3(BS), dim3(256), 0, stream,
                       cost_g, rowmin_g, rowarg_g, pairq_g);
    hipLaunchKernelGGL(loss_kernel, dim3(BS * NT), dim3(64), 0, stream,
                       rec, loc, targets, pairq_g, partial);
    hipLaunchKernelGGL(finalize_kernel, dim3(1), dim3(256), 0, stream,
                       partial, out);
}